// Round 6
// baseline (517.973 us; speedup 1.0000x reference)
//
#include <hip/hip_runtime.h>

// 3-layer MLP matvec chain, fp32 (~435 MB weights => ~69 us @ 6.3 TB/s floor).
// R5 (wave-per-row + nontemporal W): 437 us total, best yet, but per-kernel
// time is invisible (top-5 shows only 1-GiB harness poison fills). R6 is a
// MEASUREMENT round: real chain byte-identical to R5; a prepended SCRATCH
// chain (same kernels, same grids, fake weights read from the poison-filled
// workspace -- no L3 contact with real weights) adds exactly one kernel-chain
// of time. dK = dur_us(R6) - 437 = chain time. Pre-committed bands:
// dK<=100 -> kernels >=4.4 TB/s, fill-dominated, declare roofline next round;
// 100<dK<=180 -> optimize streaming; dK>180 -> structural limit, new attack.

typedef float f32x4 __attribute__((ext_vector_type(4)));

// One row per wave. grid = nrows/4 blocks of 256.
template<int K, int SQ, int INIT_OUT>
__global__ __launch_bounds__(256) void matvec_rowwave(
    const float* __restrict__ W,     // nrows x K row-major
    const float* __restrict__ xin,   // K raw pre-activation
    const float* __restrict__ bias,  // nrows
    float* __restrict__ y,           // nrows
    const float* __restrict__ b3,    // 1000 (only if INIT_OUT)
    float* __restrict__ out)         // 1000 (only if INIT_OUT)
{
    constexpr int ITER = K / 4 / 64;   // f32x4 per lane: 16 (4096) / 32 (8192)
    const int tid  = threadIdx.x;
    const int wave = tid >> 6;
    const int lane = tid & 63;
    const int row  = blockIdx.x * 4 + wave;

    const f32x4* __restrict__ W4 = (const f32x4*)(W + (size_t)row * K);
    const f32x4* __restrict__ x4 = (const f32x4*)xin;

    float acc = 0.0f;
    #pragma unroll 8
    for (int j = 0; j < ITER; ++j) {
        const int i = j * 64 + lane;         // wave covers contiguous 1 KB
        const f32x4 w = __builtin_nontemporal_load(&W4[i]);
        f32x4 v = x4[i];
        if (SQ) v *= v;
        acc += (w.x * v.x + w.y * v.y) + (w.z * v.z + w.w * v.w);
    }

    #pragma unroll
    for (int off = 32; off > 0; off >>= 1)
        acc += __shfl_down(acc, off, 64);
    if (lane == 0) y[row] = acc + bias[row];

    if (INIT_OUT && blockIdx.x < 4) {        // seed out with b3 (before layer 3)
        const int i = blockIdx.x * 256 + tid;
        if (i < 1000) out[i] = b3[i];
    }
}

// Layer 3: wave-per-(row, K-segment). grid = (1000/4) * NSEG blocks.
template<int K, int NSEG>
__global__ __launch_bounds__(256) void matvec_l3(
    const float* __restrict__ W,     // 1000 x K row-major
    const float* __restrict__ xin,   // K raw pre-activation (square applied)
    float* __restrict__ out)         // 1000, pre-seeded with b3
{
    constexpr int COLS = K / NSEG;          // 1024
    constexpr int ITER = COLS / 4 / 64;     // 4 f32x4 per lane
    const int tid  = threadIdx.x;
    const int wave = tid >> 6;
    const int lane = tid & 63;
    const int g    = blockIdx.x / NSEG;     // row group
    const int s    = blockIdx.x - g * NSEG; // K segment
    const int row  = g * 4 + wave;

    const f32x4* __restrict__ W4 = (const f32x4*)(W + (size_t)row * K + (size_t)s * COLS);
    const f32x4* __restrict__ x4 = (const f32x4*)(xin + (size_t)s * COLS);

    float acc = 0.0f;
    #pragma unroll
    for (int j = 0; j < ITER; ++j) {
        const int i = j * 64 + lane;
        const f32x4 w = __builtin_nontemporal_load(&W4[i]);
        f32x4 v = x4[i];
        v *= v;
        acc += (w.x * v.x + w.y * v.y) + (w.z * v.z + w.w * v.w);
    }

    #pragma unroll
    for (int off = 32; off > 0; off >>= 1)
        acc += __shfl_down(acc, off, 64);
    if (lane == 0) atomicAdd(&out[row], acc);
}

extern "C" void kernel_launch(void* const* d_in, const int* in_sizes, int n_in,
                              void* d_out, int out_size, void* d_ws, size_t ws_size,
                              hipStream_t stream) {
    const float* x  = (const float*)d_in[0];
    const float* W1 = (const float*)d_in[1];
    const float* b1 = (const float*)d_in[2];
    const float* W2 = (const float*)d_in[3];
    const float* b2 = (const float*)d_in[4];
    const float* W3 = (const float*)d_in[5];
    const float* b3 = (const float*)d_in[6];
    float* out = (float*)d_out;

    float* base = (float*)d_ws;
    float* h1 = base;                  // 8192 floats, raw W1@x+b1
    float* h2 = h1 + 8192;             // 8192 floats, raw W2@(h1^2)+b2

    // ---- scratch measurement chain (results unused; adds exactly one
    // kernel-chain of time so dK vs R5 = chain time) ----
    float* h1s  = base + 16384;
    float* h2s  = h1s + 8192;
    float* outs = h2s + 8192;
    // fake weights: poison-filled workspace, starting at 64 MiB, same sizes
    // and access pattern as the real weights; zero L3 contact with W1/W2/W3.
    const size_t FOFF = (size_t)64 * 1024 * 1024 / 4;
    const size_t need = (size_t)480 * 1024 * 1024;
    const float* Wf1;
    const float* Wf2;
    const float* Wf3;
    if (ws_size >= need) {
        Wf1 = base + FOFF;                          // 128 MiB
        Wf2 = Wf1 + (size_t)8192 * 4096;            // 256 MiB
        Wf3 = Wf2 + (size_t)8192 * 8192;            // 32.8 MB
    } else {                                        // fallback: reuse real W
        Wf1 = W1; Wf2 = W2; Wf3 = W3;
    }
    matvec_rowwave<4096, 0, 0><<<2048, 256, 0, stream>>>(Wf1, x,   b1, h1s, nullptr, nullptr);
    matvec_rowwave<8192, 1, 0><<<2048, 256, 0, stream>>>(Wf2, h1s, b2, h2s, nullptr, nullptr);
    matvec_l3<8192, 8><<<2000, 256, 0, stream>>>(Wf3, h2s, outs);

    // ---- real chain: byte-identical to R5 ----
    // layer 1: h1 = W1 @ x + b1          (134 MB, 2048 blocks, wave-per-row)
    matvec_rowwave<4096, 0, 0><<<2048, 256, 0, stream>>>(W1, x, b1, h1, nullptr, nullptr);
    // layer 2: h2 = W2 @ (h1*h1) + b2    (268 MB, 2048 blocks) + seed out=b3
    matvec_rowwave<8192, 1, 1><<<2048, 256, 0, stream>>>(W2, h1, b2, h2, b3, out);
    // layer 3: out += W3 @ (h2*h2)       (33 MB, 2000 blocks, K-split 8)
    matvec_l3<8192, 8><<<2000, 256, 0, stream>>>(W3, h2, out);
}